// Round 9
// baseline (629.923 us; speedup 1.0000x reference)
//
#include <hip/hip_runtime.h>
#include <hip/hip_cooperative_groups.h>
#include <stdint.h>

namespace cg = cooperative_groups;

#define HH 128
#define WW 128
#define NTILES 16
#define NPIX (HH * WW)        // 16384 = NTILES*1024 tile-space pixels
#define MAXSEG 16
#define JCH 512               // j-chunk per rank work-item
#define GB 1024               // grid blocks (4/CU on 256 CUs, co-resident)

// ---------------------------------------------------------------------------
// Stable sort key: key[i] = (bits(depth_i) << 32) | i. depths > 0, so IEEE
// bit order == float order; low 32 bits give the stable index tie-break.
// (d_j < d_i) || (d_j == d_i && j < i)  <=>  key_j < key_i.
// ---------------------------------------------------------------------------
__device__ __forceinline__ uint64_t mkkey(float d, int i) {
    return ((uint64_t)__float_as_uint(d) << 32) | (uint64_t)(uint32_t)i;
}

// ---------------------------------------------------------------------------
// Mega-kernel: entire pipeline in one cooperative launch.
//  P1 rank partial counts      (nb*ncj work-items, grid-stride)
//  P2 preprocess + scatter     (nb blocks)
//  P3 per-(tile,chunk) counts  (NTILES*ncc blocks)
//  P4 compact lists            (NTILES*ncc blocks, prefix on the fly)
//  P5 segmented render         (64*S blocks)
//  P6 combine + background     (NPIX/256 blocks)
// ---------------------------------------------------------------------------
#define CH 64
__global__ __launch_bounds__(256, 4) void mega(
        const float* __restrict__ means, const float* __restrict__ cov,
        const float* __restrict__ color, const float* __restrict__ opac,
        const float* __restrict__ depths, float* __restrict__ out,
        int* __restrict__ part, float* __restrict__ sorted,
        int* __restrict__ smask, int* __restrict__ lists,
        int* __restrict__ ccount, float4* __restrict__ part4,
        float2* __restrict__ part2, int N, int ncj, int NA, int S, int ncc) {
    cg::grid_group grid = cg::this_grid();
    int t = threadIdx.x;
    int lane = t & 63;
    int wv = t >> 6;                 // 0..3
    int nb = (N + 255) / 256;

    __shared__ int sh_w[4];
    __shared__ __align__(16) float4 s_g[CH * 3];
    __shared__ int s_idx[CH];

    // ---- P1: rank partial counts -------------------------------------
    for (int w = blockIdx.x; w < nb * ncj; w += GB) {
        int bi = w / ncj;
        int bj = w % ncj;
        int i  = bi * 256 + t;
        float di = (i < N) ? depths[i] : 0.0f;
        uint64_t ki = mkkey(di, i);

        int j0   = bj * JCH;
        int jend = min(N, j0 + JCH);
        int c0 = 0, c1 = 0, c2 = 0, c3 = 0;
        int j = j0;
        for (; j + 4 <= jend; j += 4) {
            c0 += (mkkey(depths[j + 0], j + 0) < ki);
            c1 += (mkkey(depths[j + 1], j + 1) < ki);
            c2 += (mkkey(depths[j + 2], j + 2) < ki);
            c3 += (mkkey(depths[j + 3], j + 3) < ki);
        }
        for (; j < jend; j++) c0 += (mkkey(depths[j], j) < ki);
        if (i < N) part[(size_t)bj * NA + i] = (c0 + c1) + (c2 + c3);
    }
    grid.sync();

    // ---- P2: preprocess + scatter ------------------------------------
    if (blockIdx.x < (unsigned)nb) {
        int i = blockIdx.x * 256 + t;
        if (i < N) {
            int r = 0;
            for (int b = 0; b < ncj; b++) r += part[(size_t)b * NA + i];

            float mx = means[2 * i + 0];
            float my = means[2 * i + 1];
            float c00 = cov[4 * i + 0];
            float c01 = cov[4 * i + 1];
            float c10 = cov[4 * i + 2];
            float c11 = cov[4 * i + 3];

            float det = c00 * c11 - c01 * c10;
            float mid = 0.5f * (c00 + c11);
            float s = sqrtf(fmaxf(mid * mid - det, 0.1f));
            float radii = 3.0f * ceilf(sqrtf(fmaxf(mid + s, mid - s)));

            float rminx = fminf(fmaxf(mx - radii, 0.0f), (float)(WW - 1));
            float rminy = fminf(fmaxf(my - radii, 0.0f), (float)(HH - 1));
            float rmaxx = fminf(fmaxf(mx + radii, 0.0f), (float)(WW - 1));
            float rmaxy = fminf(fmaxf(my + radii, 0.0f), (float)(HH - 1));

            float inv_det = 1.0f / det;
            float A = c11 * inv_det;
            float B = c00 * inv_det;
            float C = -(c01 + c10) * inv_det;

            int bits = 0;
            for (int ty = 0; ty < 4; ty++) {
                float h = (float)(ty * 32);
                float tly = fmaxf(rminy, h);
                float bry = fminf(rmaxy, h + 31.0f);
                bool yok = bry > tly;
                for (int tx = 0; tx < 4; tx++) {
                    float w = (float)(tx * 32);
                    float tlx = fmaxf(rminx, w);
                    float brx = fminf(rmaxx, w + 31.0f);
                    if (yok && (brx > tlx)) bits |= 1 << (ty * 4 + tx);
                }
            }

            float4* g4 = (float4*)(sorted + (size_t)r * 12);
            g4[0] = make_float4(mx, my, A, B);
            g4[1] = make_float4(C, opac[i], color[3 * i + 0], color[3 * i + 1]);
            g4[2] = make_float4(color[3 * i + 2], depths[i], 0.0f, 0.0f);
            smask[r] = bits;
        }
    }
    grid.sync();

    // ---- P3: per-(tile, chunk-of-1024) counts ------------------------
    if (blockIdx.x < (unsigned)(NTILES * ncc)) {
        int tile = blockIdx.x / ncc;
        int ch   = blockIdx.x % ncc;
        int wacc = 0;
        for (int sub = 0; sub < 4; sub++) {
            int idx = ch * 1024 + sub * 256 + t;
            int flag = (idx < N) ? ((smask[idx] >> tile) & 1) : 0;
            unsigned long long bal = __ballot(flag);
            wacc += __popcll(bal);
        }
        if (lane == 0) sh_w[wv] = wacc;
        __syncthreads();
        if (t == 0)
            ccount[tile * ncc + ch] = sh_w[0] + sh_w[1] + sh_w[2] + sh_w[3];
        __syncthreads();
    }
    grid.sync();

    // ---- P4: order-preserving list compaction ------------------------
    if (blockIdx.x < (unsigned)(NTILES * ncc)) {
        int tile = blockIdx.x / ncc;
        int ch   = blockIdx.x % ncc;
        int off = 0;
        for (int c = 0; c < ch; c++) off += ccount[tile * ncc + c];
        int* list = lists + (size_t)tile * N;
        int run = 0;
        for (int sub = 0; sub < 4; sub++) {
            int idx = ch * 1024 + sub * 256 + t;
            int flag = (idx < N) ? ((smask[idx] >> tile) & 1) : 0;
            unsigned long long bal = __ballot(flag);
            int pre = __popcll(bal & ((1ull << lane) - 1ull));
            if (lane == 0) sh_w[wv] = __popcll(bal);
            __syncthreads();
            int woff = 0;
            for (int q = 0; q < wv; q++) woff += sh_w[q];
            if (flag) list[off + run + woff + pre] = idx;
            int tot = sh_w[0] + sh_w[1] + sh_w[2] + sh_w[3];
            __syncthreads();
            run += tot;
        }
    }
    grid.sync();

    // ---- P5: segmented render ----------------------------------------
    if (blockIdx.x < (unsigned)(64 * S)) {
        int b = blockIdx.x;
        int s = b % S;
        int q = b / S;
        int tile = q >> 2;
        int sub = q & 3;
        int tx = tile & 3;
        int ty = tile >> 2;

        int p = sub * 256 + t;
        int px = p & 31;
        int py = p >> 5;
        float fx = (float)(tx * 32 + px);
        float fy = (float)(ty * 32 + py);

        int cnt = 0;
        for (int c = 0; c < ncc; c++) cnt += ccount[tile * ncc + c];
        int chunk = (cnt + S - 1) / S;
        int beg = s * chunk;
        int end = min(cnt, beg + chunk);
        const int* list = lists + (size_t)tile * N;

        float T = 1.0f;
        float ar = 0.0f, ag = 0.0f, ab = 0.0f, ad = 0.0f, aa = 0.0f;

        for (int base = beg; base < end; base += CH) {
            int m = min(CH, end - base);
            if (t < CH) s_idx[t] = (t < m) ? list[base + t] : 0;
            __syncthreads();
            if (t < m * 3) {
                int k = t / 3;
                int c = t - k * 3;
                s_g[t] = ((const float4*)(sorted + (size_t)s_idx[k] * 12))[c];
            }
            __syncthreads();
            for (int k = 0; k < m; k++) {
                float4 ga = s_g[k * 3 + 0];   // mx, my, A, B
                float4 gb = s_g[k * 3 + 1];   // C, opa, cr, cg
                float4 gc = s_g[k * 3 + 2];   // cb, depth, -, -
                float dx = fx - ga.x;
                float dy = fy - ga.y;
                float e = ga.z * dx * dx + ga.w * dy * dy + gb.x * dx * dy;
                float gw = __expf(-0.5f * e);
                float alpha = fminf(gw * gb.y, 0.99f);
                float w = T * alpha;
                ar += w * gb.z;
                ag += w * gb.w;
                ab += w * gc.x;
                ad += w * gc.y;
                aa += w;
                T *= (1.0f - alpha);
            }
            __syncthreads();
        }

        size_t o = (size_t)s * NPIX + (size_t)tile * 1024 + p;
        part4[o] = make_float4(ar, ag, ab, ad);
        part2[o] = make_float2(aa, T);
    }
    grid.sync();

    // ---- P6: combine segments + background ---------------------------
    if (blockIdx.x < (unsigned)(NPIX / 256)) {
        int pid = blockIdx.x * 256 + t;
        int tile = pid >> 10;
        int p = pid & 1023;
        int px = p & 31;
        int py = p >> 5;
        int gx = (tile & 3) * 32 + px;
        int gy = (tile >> 2) * 32 + py;

        float T = 1.0f;
        float ar = 0.0f, ag = 0.0f, ab = 0.0f, ad = 0.0f, aa = 0.0f;
        for (int s = 0; s < S; s++) {
            float4 q4 = part4[(size_t)s * NPIX + pid];
            float2 q2 = part2[(size_t)s * NPIX + pid];
            ar += T * q4.x;
            ag += T * q4.y;
            ab += T * q4.z;
            ad += T * q4.w;
            aa += T * q2.x;
            T *= q2.y;
        }

        int pidx = gy * WW + gx;
        float bgr = 1.0f - aa;
        out[pidx * 3 + 0] = ar + bgr;
        out[pidx * 3 + 1] = ag + bgr;
        out[pidx * 3 + 2] = ab + bgr;
        out[HH * WW * 3 + pidx] = ad;
        out[HH * WW * 4 + pidx] = aa;
    }
}

// ---------------------------------------------------------------------------
extern "C" void kernel_launch(void* const* d_in, const int* in_sizes, int n_in,
                              void* d_out, int out_size, void* d_ws, size_t ws_size,
                              hipStream_t stream) {
    const float* means  = (const float*)d_in[0];
    const float* cov    = (const float*)d_in[1];
    const float* color  = (const float*)d_in[2];
    const float* opac   = (const float*)d_in[3];
    const float* depths = (const float*)d_in[4];
    float* out = (float*)d_out;

    int N = in_sizes[4];
    int NA = (int)(((size_t)N + 255) / 256 * 256);   // padded N
    int ncj = (N + JCH - 1) / JCH;
    int ncc = (N + 1023) / 1024;

    // workspace layout (sections 256B-aligned)
    size_t o_part   = 0;                              // ncj * NA ints
    size_t o_sorted = o_part + (size_t)ncj * NA * 4;  // N * 12 floats
    size_t o_smask  = o_sorted + (size_t)NA * 48;     // N ints
    size_t o_lists  = o_smask + (size_t)NA * 4;       // 16 * N ints
    size_t o_cc     = o_lists + (size_t)NTILES * NA * 4; // 16*ncc ints
    size_t o_part4  = o_cc + 1024;                    // S * NPIX float4
    // part2 directly after part4 (sized by the ACTUAL S):
    //   footprint(S) = o_part4 + S*NPIX*16 + S*NPIX*8

    int S = 1;
    while (S < MAXSEG &&
           o_part4 + (size_t)(S * 2) * NPIX * 24 <= ws_size) S *= 2;
    size_t o_part2 = o_part4 + (size_t)S * NPIX * 16;

    int*    part   = (int*)((char*)d_ws + o_part);
    float*  sorted = (float*)((char*)d_ws + o_sorted);
    int*    smask  = (int*)((char*)d_ws + o_smask);
    int*    lists  = (int*)((char*)d_ws + o_lists);
    int*    ccount = (int*)((char*)d_ws + o_cc);
    float4* part4  = (float4*)((char*)d_ws + o_part4);
    float2* part2  = (float2*)((char*)d_ws + o_part2);

    void* args[] = {
        (void*)&means, (void*)&cov, (void*)&color, (void*)&opac,
        (void*)&depths, (void*)&out, (void*)&part, (void*)&sorted,
        (void*)&smask, (void*)&lists, (void*)&ccount, (void*)&part4,
        (void*)&part2, (void*)&N, (void*)&ncj, (void*)&NA, (void*)&S,
        (void*)&ncc
    };
    (void)hipLaunchCooperativeKernel((const void*)mega, dim3(GB), dim3(256),
                                     args, 0, stream);
}

// Round 16
// 352.680 us; speedup vs baseline: 1.7861x; 1.7861x over previous
//
#include <hip/hip_runtime.h>
#include <stdint.h>

#define HH 128
#define WW 128
#define NTILES 16
#define LCAP 12288            // LDS list capacity (N=12000 fits; 48 KB)
#define CH 128                // gaussians staged per chunk in kBC

// ---------------------------------------------------------------------------
// Stable sort key: key[i] = (bits(depth_i) << 32) | i. depths > 0, so IEEE
// bit order == float order; low 32 bits give the stable index tie-break.
// (d_j < d_i) || (d_j == d_i && j < i)  <=>  key_j < key_i.
// ---------------------------------------------------------------------------
__device__ __forceinline__ uint64_t mkkey(float d, int i) {
    return ((uint64_t)__float_as_uint(d) << 32) | (uint64_t)(uint32_t)i;
}

// ---------------------------------------------------------------------------
// kA: fused rank + preprocess + scatter. Block = 64 gaussians x 4 j-slices.
// Each wave counts key-compares over its quarter of [0,N) (block-uniform
// depth loads -> scalar pipe); LDS sum -> exact stable rank; wave 0 then
// preprocesses gaussian i and scatters the 12-float struct + tile mask.
// struct: [mx, my, A, B, C, opa, cr, cg, cb, depth, pad, pad]
//   gw = exp(-0.5*(A*dx^2 + B*dy^2 + C*dx*dy)), A=c11/det B=c00/det
//   C=-(c01+c10)/det
// ---------------------------------------------------------------------------
__global__ __launch_bounds__(256) void kA(const float* __restrict__ means,
                                          const float* __restrict__ cov,
                                          const float* __restrict__ color,
                                          const float* __restrict__ opac,
                                          const float* __restrict__ depths,
                                          float* __restrict__ sorted,
                                          int* __restrict__ smask, int N) {
    int t = threadIdx.x;
    int slice = t >> 6;              // wave 0..3
    int il = t & 63;
    int i = blockIdx.x * 64 + il;
    float di = (i < N) ? depths[i] : 0.0f;
    uint64_t ki = mkkey(di, i);

    int per = (N + 3) / 4;
    int j0 = slice * per;
    int jend = min(N, j0 + per);

    int c0 = 0, c1 = 0, c2 = 0, c3 = 0;
    int j = j0;
    for (; j + 4 <= jend; j += 4) {
        c0 += (mkkey(depths[j + 0], j + 0) < ki);
        c1 += (mkkey(depths[j + 1], j + 1) < ki);
        c2 += (mkkey(depths[j + 2], j + 2) < ki);
        c3 += (mkkey(depths[j + 3], j + 3) < ki);
    }
    for (; j < jend; j++) c0 += (mkkey(depths[j], j) < ki);

    __shared__ int s_cnt[4][64];
    s_cnt[slice][il] = (c0 + c1) + (c2 + c3);
    __syncthreads();

    if (slice == 0 && i < N) {
        int r = s_cnt[0][il] + s_cnt[1][il] + s_cnt[2][il] + s_cnt[3][il];

        float mx = means[2 * i + 0];
        float my = means[2 * i + 1];
        float c00 = cov[4 * i + 0];
        float c01 = cov[4 * i + 1];
        float c10 = cov[4 * i + 2];
        float c11 = cov[4 * i + 3];

        float det = c00 * c11 - c01 * c10;
        float mid = 0.5f * (c00 + c11);
        float s = sqrtf(fmaxf(mid * mid - det, 0.1f));
        float radii = 3.0f * ceilf(sqrtf(fmaxf(mid + s, mid - s)));

        float rminx = fminf(fmaxf(mx - radii, 0.0f), (float)(WW - 1));
        float rminy = fminf(fmaxf(my - radii, 0.0f), (float)(HH - 1));
        float rmaxx = fminf(fmaxf(mx + radii, 0.0f), (float)(WW - 1));
        float rmaxy = fminf(fmaxf(my + radii, 0.0f), (float)(HH - 1));

        float inv_det = 1.0f / det;
        float A = c11 * inv_det;
        float B = c00 * inv_det;
        float C = -(c01 + c10) * inv_det;

        int bits = 0;
        for (int ty = 0; ty < 4; ty++) {
            float h = (float)(ty * 32);
            float tly = fmaxf(rminy, h);
            float bry = fminf(rmaxy, h + 31.0f);
            bool yok = bry > tly;
            for (int tx = 0; tx < 4; tx++) {
                float w = (float)(tx * 32);
                float tlx = fmaxf(rminx, w);
                float brx = fminf(rmaxx, w + 31.0f);
                if (yok && (brx > tlx)) bits |= 1 << (ty * 4 + tx);
            }
        }

        float4* g4 = (float4*)(sorted + (size_t)r * 12);
        g4[0] = make_float4(mx, my, A, B);
        g4[1] = make_float4(C, opac[i], color[3 * i + 0], color[3 * i + 1]);
        g4[2] = make_float4(color[3 * i + 2], depths[i], 0.0f, 0.0f);
        smask[r] = bits;
    }
}

// ---------------------------------------------------------------------------
// kBC: fused compact + render + output. One block (1024 threads = 16 waves)
// per tile. Phase 1: ballot-scan compaction of the tile's depth-ordered
// index list into LDS. Phase 2: thread = pixel, serial front-to-back
// composite over the full list (exact reference order) in CH-gaussian
// LDS-staged chunks. Phase 3: write img_c / img_d / img_a.
// Static LDS: 48K (list) + 6K (stage) + ~140B  ≈ 55.5 KB.
// ---------------------------------------------------------------------------
__global__ __launch_bounds__(1024) void kBC(const float* __restrict__ sorted,
                                            const int* __restrict__ smask,
                                            float* __restrict__ out, int N) {
    int tile = blockIdx.x;
    int t = threadIdx.x;
    int lane = t & 63;
    int wv = t >> 6;                 // 0..15

    __shared__ int s_list[LCAP];
    __shared__ int wsum[16];
    __shared__ int woff[16];
    __shared__ int s_run;
    __shared__ __align__(16) float4 s_g[CH * 3];

    if (t == 0) s_run = 0;
    __syncthreads();

    // ---- Phase 1: order-preserving compaction into LDS ----
    for (int base = 0; base < N; base += 1024) {
        int idx = base + t;
        int flag = (idx < N) ? ((smask[idx] >> tile) & 1) : 0;
        unsigned long long bal = __ballot(flag);
        int pre = __popcll(bal & ((1ull << lane) - 1ull));
        if (lane == 63) wsum[wv] = pre + flag;
        __syncthreads();
        if (wv == 0 && lane < 16) {
            int v = 0;
            for (int q = 0; q < lane; q++) v += wsum[q];
            woff[lane] = v;
        }
        __syncthreads();
        int run = s_run;
        if (flag) {
            int pos = run + woff[wv] + pre;
            if (pos < LCAP) s_list[pos] = idx;
        }
        __syncthreads();
        if (t == 0) s_run = run + woff[15] + wsum[15];
        __syncthreads();
    }
    int cnt = min(s_run, LCAP);

    // ---- Phase 2: serial composite, thread = pixel ----
    int px = t & 31;
    int py = t >> 5;
    float fx = (float)((tile & 3) * 32 + px);
    float fy = (float)((tile >> 2) * 32 + py);

    float T = 1.0f;
    float ar = 0.0f, ag = 0.0f, ab = 0.0f, ad = 0.0f, aa = 0.0f;

    for (int base = 0; base < cnt; base += CH) {
        int m = min(CH, cnt - base);
        __syncthreads();             // protect s_g from previous iteration
        if (t < m * 3) {
            int k = t / 3;
            int c = t - k * 3;
            s_g[t] = ((const float4*)(sorted + (size_t)s_list[base + k] * 12))[c];
        }
        __syncthreads();
        for (int k = 0; k < m; k++) {
            float4 ga = s_g[k * 3 + 0];   // mx, my, A, B
            float4 gb = s_g[k * 3 + 1];   // C, opa, cr, cg
            float4 gc = s_g[k * 3 + 2];   // cb, depth, -, -
            float dx = fx - ga.x;
            float dy = fy - ga.y;
            float e = ga.z * dx * dx + ga.w * dy * dy + gb.x * dx * dy;
            float gw = __expf(-0.5f * e);
            float alpha = fminf(gw * gb.y, 0.99f);
            float w = T * alpha;
            ar += w * gb.z;
            ag += w * gb.w;
            ab += w * gc.x;
            ad += w * gc.y;
            aa += w;
            T *= (1.0f - alpha);
        }
    }

    // ---- Phase 3: output ----
    int gx = (tile & 3) * 32 + px;
    int gy = (tile >> 2) * 32 + py;
    int pidx = gy * WW + gx;
    float bgr = 1.0f - aa;
    out[pidx * 3 + 0] = ar + bgr;
    out[pidx * 3 + 1] = ag + bgr;
    out[pidx * 3 + 2] = ab + bgr;
    out[HH * WW * 3 + pidx] = ad;
    out[HH * WW * 4 + pidx] = aa;
}

// ---------------------------------------------------------------------------
extern "C" void kernel_launch(void* const* d_in, const int* in_sizes, int n_in,
                              void* d_out, int out_size, void* d_ws, size_t ws_size,
                              hipStream_t stream) {
    const float* means  = (const float*)d_in[0];
    const float* cov    = (const float*)d_in[1];
    const float* color  = (const float*)d_in[2];
    const float* opac   = (const float*)d_in[3];
    const float* depths = (const float*)d_in[4];
    float* out = (float*)d_out;

    int N = in_sizes[4];
    size_t NA = ((size_t)N + 255) / 256 * 256;

    // workspace: sorted structs + tile masks only
    float* sorted = (float*)d_ws;                       // N * 12 floats
    int*   smask  = (int*)((char*)d_ws + NA * 48);      // N ints

    int nb64 = (N + 63) / 64;

    kA<<<nb64, 256, 0, stream>>>(means, cov, color, opac, depths,
                                 sorted, smask, N);
    kBC<<<NTILES, 1024, 0, stream>>>(sorted, smask, out, N);
}

// Round 17
// 156.119 us; speedup vs baseline: 4.0349x; 2.2590x over previous
//
#include <hip/hip_runtime.h>
#include <stdint.h>

#define HH 128
#define WW 128
#define NTILES 16
#define NPIX (HH * WW)        // 16384 tile-space pixels
#define SEG 16                // depth segments
#define LCAP 12288            // per-tile struct capacity (N=12000 fits)
#define JCH 512               // j-chunk per k1 block

// ---------------------------------------------------------------------------
// Stable sort key: key[i] = (bits(depth_i) << 32) | i. depths > 0, so IEEE
// bit order == float order; low 32 bits give the stable index tie-break.
// (d_j < d_i) || (d_j == d_i && j < i)  <=>  key_j < key_i.
// ---------------------------------------------------------------------------
__device__ __forceinline__ uint64_t mkkey(float d, int i) {
    return ((uint64_t)__float_as_uint(d) << 32) | (uint64_t)(uint32_t)i;
}

// ---------------------------------------------------------------------------
// k1: rank partial counts. Block (bi,bj): lanes hold i-keys; loop over the
// bj-th j-chunk (block-uniform loads -> scalar pipe). 1128 blocks.
// part[bj*NA + i] = count.   [proven in the 140us run]
// ---------------------------------------------------------------------------
__global__ __launch_bounds__(256) void k1_rank(const float* __restrict__ depths,
                                               int* __restrict__ part,
                                               int N, int ncj, int NA) {
    int bi = blockIdx.x / ncj;
    int bj = blockIdx.x % ncj;
    int t  = threadIdx.x;
    int i  = bi * 256 + t;
    float di = (i < N) ? depths[i] : 0.0f;
    uint64_t ki = mkkey(di, i);

    int j0   = bj * JCH;
    int jend = min(N, j0 + JCH);

    int c0 = 0, c1 = 0, c2 = 0, c3 = 0;
    int j = j0;
    for (; j + 4 <= jend; j += 4) {
        c0 += (mkkey(depths[j + 0], j + 0) < ki);
        c1 += (mkkey(depths[j + 1], j + 1) < ki);
        c2 += (mkkey(depths[j + 2], j + 2) < ki);
        c3 += (mkkey(depths[j + 3], j + 3) < ki);
    }
    for (; j < jend; j++) c0 += (mkkey(depths[j], j) < ki);

    if (i < N) part[(size_t)bj * NA + i] = (c0 + c1) + (c2 + c3);
}

// ---------------------------------------------------------------------------
// k2: rank[i] = sum of partials; preprocess gaussian i; scatter 12-float
// struct to sorted[rank[i]]; write 16-bit tile mask to smask[rank[i]].
// struct: [mx, my, A, B, C, opa, cr, cg, cb, depth, pad, pad]
// ---------------------------------------------------------------------------
__global__ __launch_bounds__(256) void k2_scatter(const float* __restrict__ means,
                                                  const float* __restrict__ cov,
                                                  const float* __restrict__ color,
                                                  const float* __restrict__ opac,
                                                  const float* __restrict__ depths,
                                                  const int* __restrict__ part,
                                                  float* __restrict__ sorted,
                                                  int* __restrict__ smask,
                                                  int N, int ncj, int NA) {
    int i = blockIdx.x * blockDim.x + threadIdx.x;
    if (i >= N) return;

    int r = 0;
    for (int b = 0; b < ncj; b++) r += part[(size_t)b * NA + i];

    float mx = means[2 * i + 0];
    float my = means[2 * i + 1];
    float c00 = cov[4 * i + 0];
    float c01 = cov[4 * i + 1];
    float c10 = cov[4 * i + 2];
    float c11 = cov[4 * i + 3];

    float det = c00 * c11 - c01 * c10;
    float mid = 0.5f * (c00 + c11);
    float s = sqrtf(fmaxf(mid * mid - det, 0.1f));
    float radii = 3.0f * ceilf(sqrtf(fmaxf(mid + s, mid - s)));

    float rminx = fminf(fmaxf(mx - radii, 0.0f), (float)(WW - 1));
    float rminy = fminf(fmaxf(my - radii, 0.0f), (float)(HH - 1));
    float rmaxx = fminf(fmaxf(mx + radii, 0.0f), (float)(WW - 1));
    float rmaxy = fminf(fmaxf(my + radii, 0.0f), (float)(HH - 1));

    float inv_det = 1.0f / det;
    float A = c11 * inv_det;
    float B = c00 * inv_det;
    float C = -(c01 + c10) * inv_det;

    int bits = 0;
    for (int ty = 0; ty < 4; ty++) {
        float h = (float)(ty * 32);
        float tly = fmaxf(rminy, h);
        float bry = fminf(rmaxy, h + 31.0f);
        bool yok = bry > tly;
        for (int tx = 0; tx < 4; tx++) {
            float w = (float)(tx * 32);
            float tlx = fmaxf(rminx, w);
            float brx = fminf(rmaxx, w + 31.0f);
            if (yok && (brx > tlx)) bits |= 1 << (ty * 4 + tx);
        }
    }

    float4* g4 = (float4*)(sorted + (size_t)r * 12);
    g4[0] = make_float4(mx, my, A, B);
    g4[1] = make_float4(C, opac[i], color[3 * i + 0], color[3 * i + 1]);
    g4[2] = make_float4(color[3 * i + 2], depths[i], 0.0f, 0.0f);
    smask[r] = bits;
}

// ---------------------------------------------------------------------------
// k3: per-tile compaction, gathering STRUCTS into a contiguous per-tile
// array tlist[tile][pos] (12 floats each). One block (1024 thr) per tile;
// ballot+popcount scan; gather reads from `sorted` are rank-ascending.
// ---------------------------------------------------------------------------
__global__ __launch_bounds__(1024) void k3_gather(const float* __restrict__ sorted,
                                                  const int* __restrict__ smask,
                                                  float* __restrict__ tlist,
                                                  int* __restrict__ counts,
                                                  int N) {
    int tile = blockIdx.x;
    int t = threadIdx.x;
    int lane = t & 63;
    int wv = t >> 6;            // 0..15

    __shared__ int wsum[16];
    __shared__ int woff[16];
    __shared__ int s_run;
    if (t == 0) s_run = 0;
    __syncthreads();

    float* dst = tlist + (size_t)tile * LCAP * 12;

    for (int base = 0; base < N; base += 1024) {
        int idx = base + t;
        int flag = (idx < N) ? ((smask[idx] >> tile) & 1) : 0;
        unsigned long long bal = __ballot(flag);
        int pre = __popcll(bal & ((1ull << lane) - 1ull));
        if (lane == 63) wsum[wv] = pre + flag;
        __syncthreads();
        if (wv == 0 && lane < 16) {
            int v = 0;
            for (int q = 0; q < lane; q++) v += wsum[q];
            woff[lane] = v;
        }
        __syncthreads();
        int run = s_run;
        if (flag) {
            int pos = run + woff[wv] + pre;
            const float4* src = (const float4*)(sorted + (size_t)idx * 12);
            float4* d4 = (float4*)(dst + (size_t)pos * 12);
            d4[0] = src[0];
            d4[1] = src[1];
            d4[2] = src[2];
        }
        __syncthreads();
        if (t == 0) s_run = run + woff[15] + wsum[15];
        __syncthreads();
    }
    if (t == 0) counts[tile] = s_run;
}

// ---------------------------------------------------------------------------
// k4: segmented render, 2 pixels/thread, NO LDS. Grid = 16 tiles x 2 halves
// x SEG segments = 512 blocks. Struct reads are wave-uniform sequential
// global addresses (scalarized / L1-broadcast). Front-to-back compositing
// is associative under merge(P,Q)=(P.acc+P.T*Q.acc, P.T*Q.T).
// partials: part4[s*NPIX+pid]=(r,g,b,d), part2[s*NPIX+pid]=(a,T)
// ---------------------------------------------------------------------------
__global__ __launch_bounds__(256) void k4_render(const float* __restrict__ tlist,
                                                 const int* __restrict__ counts,
                                                 float4* __restrict__ part4,
                                                 float2* __restrict__ part2) {
    int b = blockIdx.x;
    int s = b & (SEG - 1);
    int q = b / SEG;               // 0..31 = tile*2 + half
    int tile = q >> 1;
    int half = q & 1;
    int t = threadIdx.x;

    int p0 = half * 512 + t;       // pixel in tile (0..1023)
    int p1 = p0 + 256;             // 8 rows below; same column
    int px  = p0 & 31;
    int py0 = p0 >> 5;
    int py1 = p1 >> 5;
    float fx  = (float)((tile & 3) * 32 + px);
    float fy0 = (float)((tile >> 2) * 32 + py0);
    float fy1 = (float)((tile >> 2) * 32 + py1);

    int cnt = counts[tile];
    int chunk = (cnt + SEG - 1) / SEG;
    int beg = s * chunk;
    int end = min(cnt, beg + chunk);
    const float* g = tlist + (size_t)tile * LCAP * 12;

    float T0 = 1.0f, ar0 = 0.0f, ag0 = 0.0f, ab0 = 0.0f, ad0 = 0.0f, aa0 = 0.0f;
    float T1 = 1.0f, ar1 = 0.0f, ag1 = 0.0f, ab1 = 0.0f, ad1 = 0.0f, aa1 = 0.0f;

    for (int k = beg; k < end; k++) {
        const float4* g4 = (const float4*)(g + (size_t)k * 12);
        float4 ga = g4[0];   // mx, my, A, B
        float4 gb = g4[1];   // C, opa, cr, cg
        float4 gc = g4[2];   // cb, depth, -, -
        float dx  = fx - ga.x;
        float dx2 = dx * dx;
        float cdx = gb.x * dx;
        float dy0 = fy0 - ga.y;
        float dy1 = fy1 - ga.y;
        float e0 = ga.z * dx2 + ga.w * dy0 * dy0 + cdx * dy0;
        float e1 = ga.z * dx2 + ga.w * dy1 * dy1 + cdx * dy1;
        float gw0 = __expf(-0.5f * e0);
        float gw1 = __expf(-0.5f * e1);
        float a0 = fminf(gw0 * gb.y, 0.99f);
        float a1 = fminf(gw1 * gb.y, 0.99f);
        float w0 = T0 * a0;
        float w1 = T1 * a1;
        ar0 += w0 * gb.z;  ar1 += w1 * gb.z;
        ag0 += w0 * gb.w;  ag1 += w1 * gb.w;
        ab0 += w0 * gc.x;  ab1 += w1 * gc.x;
        ad0 += w0 * gc.y;  ad1 += w1 * gc.y;
        aa0 += w0;         aa1 += w1;
        T0 *= (1.0f - a0);
        T1 *= (1.0f - a1);
    }

    size_t o0 = (size_t)s * NPIX + (size_t)tile * 1024 + p0;
    size_t o1 = o0 + 256;
    part4[o0] = make_float4(ar0, ag0, ab0, ad0);
    part2[o0] = make_float2(aa0, T0);
    part4[o1] = make_float4(ar1, ag1, ab1, ad1);
    part2[o1] = make_float2(aa1, T1);
}

// ---------------------------------------------------------------------------
// k5: combine the SEG depth-segments per pixel (in order) + background.
// ---------------------------------------------------------------------------
__global__ __launch_bounds__(256) void k5_combine(const float4* __restrict__ part4,
                                                  const float2* __restrict__ part2,
                                                  float* __restrict__ out) {
    int pid = blockIdx.x * 256 + threadIdx.x;   // tile-space pixel id
    int tile = pid >> 10;
    int p = pid & 1023;
    int px = p & 31;
    int py = p >> 5;
    int gx = (tile & 3) * 32 + px;
    int gy = (tile >> 2) * 32 + py;

    float T = 1.0f;
    float ar = 0.0f, ag = 0.0f, ab = 0.0f, ad = 0.0f, aa = 0.0f;
    for (int s = 0; s < SEG; s++) {
        float4 q4 = part4[(size_t)s * NPIX + pid];
        float2 q2 = part2[(size_t)s * NPIX + pid];
        ar += T * q4.x;
        ag += T * q4.y;
        ab += T * q4.z;
        ad += T * q4.w;
        aa += T * q2.x;
        T *= q2.y;
    }

    int pidx = gy * WW + gx;
    float bgr = 1.0f - aa;
    out[pidx * 3 + 0] = ar + bgr;
    out[pidx * 3 + 1] = ag + bgr;
    out[pidx * 3 + 2] = ab + bgr;
    out[HH * WW * 3 + pidx] = ad;
    out[HH * WW * 4 + pidx] = aa;
}

// ---------------------------------------------------------------------------
extern "C" void kernel_launch(void* const* d_in, const int* in_sizes, int n_in,
                              void* d_out, int out_size, void* d_ws, size_t ws_size,
                              hipStream_t stream) {
    const float* means  = (const float*)d_in[0];
    const float* cov    = (const float*)d_in[1];
    const float* color  = (const float*)d_in[2];
    const float* opac   = (const float*)d_in[3];
    const float* depths = (const float*)d_in[4];
    float* out = (float*)d_out;

    int N = in_sizes[4];
    int NA = (int)(((size_t)N + 255) / 256 * 256);
    int nb  = (N + 255) / 256;
    int ncj = (N + JCH - 1) / JCH;

    // workspace layout (sections 256B-aligned); total ~17.5 MB
    size_t o_part   = 0;                                  // ncj * NA ints
    size_t o_sorted = o_part + (size_t)ncj * NA * 4;      // N * 12 floats
    size_t o_smask  = o_sorted + (size_t)NA * 48;         // N ints
    size_t o_tlist  = o_smask + (size_t)NA * 4;           // 16 * LCAP * 12 floats
    size_t o_counts = o_tlist + (size_t)NTILES * LCAP * 48; // 16 ints
    size_t o_part4  = o_counts + 256;                     // SEG*NPIX float4
    size_t o_part2  = o_part4 + (size_t)SEG * NPIX * 16;  // SEG*NPIX float2

    int*    part   = (int*)((char*)d_ws + o_part);
    float*  sorted = (float*)((char*)d_ws + o_sorted);
    int*    smask  = (int*)((char*)d_ws + o_smask);
    float*  tlist  = (float*)((char*)d_ws + o_tlist);
    int*    counts = (int*)((char*)d_ws + o_counts);
    float4* part4  = (float4*)((char*)d_ws + o_part4);
    float2* part2  = (float2*)((char*)d_ws + o_part2);

    k1_rank<<<nb * ncj, 256, 0, stream>>>(depths, part, N, ncj, NA);
    k2_scatter<<<nb, 256, 0, stream>>>(means, cov, color, opac, depths, part,
                                       sorted, smask, N, ncj, NA);
    k3_gather<<<NTILES, 1024, 0, stream>>>(sorted, smask, tlist, counts, N);
    k4_render<<<NTILES * 2 * SEG, 256, 0, stream>>>(tlist, counts, part4, part2);
    k5_combine<<<NPIX / 256, 256, 0, stream>>>(part4, part2, out);
}

// Round 18
// 151.564 us; speedup vs baseline: 4.1561x; 1.0300x over previous
//
#include <hip/hip_runtime.h>
#include <stdint.h>

#define HH 128
#define WW 128
#define NTILES 16
#define NPIX (HH * WW)        // 16384 tile-space pixels
#define SEG 16                // depth segments
#define JCH 512               // j-chunk per k1 block

// ---------------------------------------------------------------------------
// Stable sort key: key[i] = (bits(depth_i) << 32) | i. depths > 0, so IEEE
// bit order == float order; low 32 bits give the stable index tie-break.
// ---------------------------------------------------------------------------
__device__ __forceinline__ uint64_t mkkey(float d, int i) {
    return ((uint64_t)__float_as_uint(d) << 32) | (uint64_t)(uint32_t)i;
}

// ---------------------------------------------------------------------------
// k1: rank partial counts. Block (bi,bj): lanes hold i-keys; loop over the
// bj-th j-chunk (block-uniform loads -> scalar pipe). [proven, round 8]
// ---------------------------------------------------------------------------
__global__ __launch_bounds__(256) void k1_rank(const float* __restrict__ depths,
                                               int* __restrict__ part,
                                               int N, int ncj, int NA) {
    int bi = blockIdx.x / ncj;
    int bj = blockIdx.x % ncj;
    int t  = threadIdx.x;
    int i  = bi * 256 + t;
    float di = (i < N) ? depths[i] : 0.0f;
    uint64_t ki = mkkey(di, i);

    int j0   = bj * JCH;
    int jend = min(N, j0 + JCH);

    int c0 = 0, c1 = 0, c2 = 0, c3 = 0;
    int j = j0;
    for (; j + 4 <= jend; j += 4) {
        c0 += (mkkey(depths[j + 0], j + 0) < ki);
        c1 += (mkkey(depths[j + 1], j + 1) < ki);
        c2 += (mkkey(depths[j + 2], j + 2) < ki);
        c3 += (mkkey(depths[j + 3], j + 3) < ki);
    }
    for (; j < jend; j++) c0 += (mkkey(depths[j], j) < ki);

    if (i < N) part[(size_t)bj * NA + i] = (c0 + c1) + (c2 + c3);
}

// ---------------------------------------------------------------------------
// k2: rank[i] = sum of partials; preprocess; scatter struct + tile mask.
// struct: [mx, my, A, B, C, opa, cr, cg, cb, depth, pad, pad]  [proven]
// ---------------------------------------------------------------------------
__global__ __launch_bounds__(256) void k2_scatter(const float* __restrict__ means,
                                                  const float* __restrict__ cov,
                                                  const float* __restrict__ color,
                                                  const float* __restrict__ opac,
                                                  const float* __restrict__ depths,
                                                  const int* __restrict__ part,
                                                  float* __restrict__ sorted,
                                                  int* __restrict__ smask,
                                                  int N, int ncj, int NA) {
    int i = blockIdx.x * blockDim.x + threadIdx.x;
    if (i >= N) return;

    int r = 0;
    for (int b = 0; b < ncj; b++) r += part[(size_t)b * NA + i];

    float mx = means[2 * i + 0];
    float my = means[2 * i + 1];
    float c00 = cov[4 * i + 0];
    float c01 = cov[4 * i + 1];
    float c10 = cov[4 * i + 2];
    float c11 = cov[4 * i + 3];

    float det = c00 * c11 - c01 * c10;
    float mid = 0.5f * (c00 + c11);
    float s = sqrtf(fmaxf(mid * mid - det, 0.1f));
    float radii = 3.0f * ceilf(sqrtf(fmaxf(mid + s, mid - s)));

    float rminx = fminf(fmaxf(mx - radii, 0.0f), (float)(WW - 1));
    float rminy = fminf(fmaxf(my - radii, 0.0f), (float)(HH - 1));
    float rmaxx = fminf(fmaxf(mx + radii, 0.0f), (float)(WW - 1));
    float rmaxy = fminf(fmaxf(my + radii, 0.0f), (float)(HH - 1));

    float inv_det = 1.0f / det;
    float A = c11 * inv_det;
    float B = c00 * inv_det;
    float C = -(c01 + c10) * inv_det;

    int bits = 0;
    for (int ty = 0; ty < 4; ty++) {
        float h = (float)(ty * 32);
        float tly = fmaxf(rminy, h);
        float bry = fminf(rmaxy, h + 31.0f);
        bool yok = bry > tly;
        for (int tx = 0; tx < 4; tx++) {
            float w = (float)(tx * 32);
            float tlx = fmaxf(rminx, w);
            float brx = fminf(rmaxx, w + 31.0f);
            if (yok && (brx > tlx)) bits |= 1 << (ty * 4 + tx);
        }
    }

    float4* g4 = (float4*)(sorted + (size_t)r * 12);
    g4[0] = make_float4(mx, my, A, B);
    g4[1] = make_float4(C, opac[i], color[3 * i + 0], color[3 * i + 1]);
    g4[2] = make_float4(color[3 * i + 2], depths[i], 0.0f, 0.0f);
    smask[r] = bits;
}

// ---------------------------------------------------------------------------
// k3: per-tile order-preserving index compaction (lists only, ~0.8 MB).
// One block (1024 threads = 16 waves) per tile. [proven, round 8]
// ---------------------------------------------------------------------------
__global__ __launch_bounds__(1024) void k3_compact(const int* __restrict__ smask,
                                                   int* __restrict__ lists,
                                                   int* __restrict__ counts,
                                                   int N) {
    int tile = blockIdx.x;
    int t = threadIdx.x;
    int lane = t & 63;
    int wv = t >> 6;            // 0..15

    __shared__ int wsum[16];
    __shared__ int woff[16];
    __shared__ int s_run;
    if (t == 0) s_run = 0;
    __syncthreads();

    int* list = lists + (size_t)tile * N;

    for (int base = 0; base < N; base += 1024) {
        int idx = base + t;
        int flag = (idx < N) ? ((smask[idx] >> tile) & 1) : 0;
        unsigned long long bal = __ballot(flag);
        int pre = __popcll(bal & ((1ull << lane) - 1ull));
        if (lane == 63) wsum[wv] = pre + flag;
        __syncthreads();
        if (wv == 0 && lane < 16) {
            int v = 0;
            for (int q = 0; q < lane; q++) v += wsum[q];
            woff[lane] = v;
        }
        __syncthreads();
        int run = s_run;
        if (flag) list[run + woff[wv] + pre] = idx;
        __syncthreads();
        if (t == 0) s_run = run + woff[15] + wsum[15];
        __syncthreads();
    }
    if (t == 0) counts[tile] = s_run;
}

// ---------------------------------------------------------------------------
// k4: segmented render, 2 pixels/thread, NO LDS. Grid = 16 tiles x 2 halves
// x SEG segments = 512 blocks. Index + struct reads are wave-uniform
// (scalarized / L1-broadcast). Compositing is associative under
// merge(P,Q)=(P.acc+P.T*Q.acc, P.T*Q.T). [k4-noLDS measured faster, r17]
// ---------------------------------------------------------------------------
__global__ __launch_bounds__(256) void k4_render(const float* __restrict__ sorted,
                                                 const int* __restrict__ lists,
                                                 const int* __restrict__ counts,
                                                 float4* __restrict__ part4,
                                                 float2* __restrict__ part2,
                                                 int N) {
    int b = blockIdx.x;
    int s = b & (SEG - 1);
    int q = b / SEG;               // 0..31 = tile*2 + half
    int tile = q >> 1;
    int half = q & 1;
    int t = threadIdx.x;

    int p0 = half * 512 + t;       // pixel in tile (0..1023)
    int p1 = p0 + 256;             // 8 rows below, same column
    int px  = p0 & 31;
    int py0 = p0 >> 5;
    int py1 = p1 >> 5;
    float fx  = (float)((tile & 3) * 32 + px);
    float fy0 = (float)((tile >> 2) * 32 + py0);
    float fy1 = (float)((tile >> 2) * 32 + py1);

    int cnt = counts[tile];
    int chunk = (cnt + SEG - 1) / SEG;
    int beg = s * chunk;
    int end = min(cnt, beg + chunk);
    const int* list = lists + (size_t)tile * N;

    float T0 = 1.0f, ar0 = 0.0f, ag0 = 0.0f, ab0 = 0.0f, ad0 = 0.0f, aa0 = 0.0f;
    float T1 = 1.0f, ar1 = 0.0f, ag1 = 0.0f, ab1 = 0.0f, ad1 = 0.0f, aa1 = 0.0f;

    for (int k = beg; k < end; k++) {
        int idx = list[k];                         // uniform scalar load
        const float4* g4 = (const float4*)(sorted + (size_t)idx * 12);
        float4 ga = g4[0];   // mx, my, A, B
        float4 gb = g4[1];   // C, opa, cr, cg
        float4 gc = g4[2];   // cb, depth, -, -
        float dx  = fx - ga.x;
        float dx2 = dx * dx;
        float cdx = gb.x * dx;
        float dy0 = fy0 - ga.y;
        float dy1 = fy1 - ga.y;
        float e0 = ga.z * dx2 + ga.w * dy0 * dy0 + cdx * dy0;
        float e1 = ga.z * dx2 + ga.w * dy1 * dy1 + cdx * dy1;
        float gw0 = __expf(-0.5f * e0);
        float gw1 = __expf(-0.5f * e1);
        float a0 = fminf(gw0 * gb.y, 0.99f);
        float a1 = fminf(gw1 * gb.y, 0.99f);
        float w0 = T0 * a0;
        float w1 = T1 * a1;
        ar0 += w0 * gb.z;  ar1 += w1 * gb.z;
        ag0 += w0 * gb.w;  ag1 += w1 * gb.w;
        ab0 += w0 * gc.x;  ab1 += w1 * gc.x;
        ad0 += w0 * gc.y;  ad1 += w1 * gc.y;
        aa0 += w0;         aa1 += w1;
        T0 *= (1.0f - a0);
        T1 *= (1.0f - a1);
    }

    size_t o0 = (size_t)s * NPIX + (size_t)tile * 1024 + p0;
    size_t o1 = o0 + 256;
    part4[o0] = make_float4(ar0, ag0, ab0, ad0);
    part2[o0] = make_float2(aa0, T0);
    part4[o1] = make_float4(ar1, ag1, ab1, ad1);
    part2[o1] = make_float2(aa1, T1);
}

// ---------------------------------------------------------------------------
// k5: combine the SEG depth-segments per pixel (in order) + background.
// ---------------------------------------------------------------------------
__global__ __launch_bounds__(256) void k5_combine(const float4* __restrict__ part4,
                                                  const float2* __restrict__ part2,
                                                  float* __restrict__ out) {
    int pid = blockIdx.x * 256 + threadIdx.x;   // tile-space pixel id
    int tile = pid >> 10;
    int p = pid & 1023;
    int px = p & 31;
    int py = p >> 5;
    int gx = (tile & 3) * 32 + px;
    int gy = (tile >> 2) * 32 + py;

    float T = 1.0f;
    float ar = 0.0f, ag = 0.0f, ab = 0.0f, ad = 0.0f, aa = 0.0f;
    for (int s = 0; s < SEG; s++) {
        float4 q4 = part4[(size_t)s * NPIX + pid];
        float2 q2 = part2[(size_t)s * NPIX + pid];
        ar += T * q4.x;
        ag += T * q4.y;
        ab += T * q4.z;
        ad += T * q4.w;
        aa += T * q2.x;
        T *= q2.y;
    }

    int pidx = gy * WW + gx;
    float bgr = 1.0f - aa;
    out[pidx * 3 + 0] = ar + bgr;
    out[pidx * 3 + 1] = ag + bgr;
    out[pidx * 3 + 2] = ab + bgr;
    out[HH * WW * 3 + pidx] = ad;
    out[HH * WW * 4 + pidx] = aa;
}

// ---------------------------------------------------------------------------
extern "C" void kernel_launch(void* const* d_in, const int* in_sizes, int n_in,
                              void* d_out, int out_size, void* d_ws, size_t ws_size,
                              hipStream_t stream) {
    const float* means  = (const float*)d_in[0];
    const float* cov    = (const float*)d_in[1];
    const float* color  = (const float*)d_in[2];
    const float* opac   = (const float*)d_in[3];
    const float* depths = (const float*)d_in[4];
    float* out = (float*)d_out;

    int N = in_sizes[4];
    int NA = (int)(((size_t)N + 255) / 256 * 256);
    int nb  = (N + 255) / 256;
    int ncj = (N + JCH - 1) / JCH;

    // workspace layout (sections 256B-aligned)
    size_t o_part   = 0;                                  // ncj * NA ints
    size_t o_sorted = o_part + (size_t)ncj * NA * 4;      // N * 12 floats
    size_t o_smask  = o_sorted + (size_t)NA * 48;         // N ints
    size_t o_lists  = o_smask + (size_t)NA * 4;           // 16 * N ints
    size_t o_counts = o_lists + (size_t)NTILES * NA * 4;  // 16 ints
    size_t o_part4  = o_counts + 256;                     // SEG*NPIX float4
    size_t o_part2  = o_part4 + (size_t)SEG * NPIX * 16;  // SEG*NPIX float2

    int*    part   = (int*)((char*)d_ws + o_part);
    float*  sorted = (float*)((char*)d_ws + o_sorted);
    int*    smask  = (int*)((char*)d_ws + o_smask);
    int*    lists  = (int*)((char*)d_ws + o_lists);
    int*    counts = (int*)((char*)d_ws + o_counts);
    float4* part4  = (float4*)((char*)d_ws + o_part4);
    float2* part2  = (float2*)((char*)d_ws + o_part2);

    k1_rank<<<nb * ncj, 256, 0, stream>>>(depths, part, N, ncj, NA);
    k2_scatter<<<nb, 256, 0, stream>>>(means, cov, color, opac, depths, part,
                                       sorted, smask, N, ncj, NA);
    k3_compact<<<NTILES, 1024, 0, stream>>>(smask, lists, counts, N);
    k4_render<<<NTILES * 2 * SEG, 256, 0, stream>>>(sorted, lists, counts,
                                                    part4, part2, N);
    k5_combine<<<NPIX / 256, 256, 0, stream>>>(part4, part2, out);
}